// Round 7
// baseline (17745.857 us; speedup 1.0000x reference)
//
#include <hip/hip_runtime.h>
#include <stdint.h>
#include <math.h>

// plmDCA one Gibbs sweep — bitwise-faithful replay of the JAX reference.
// Confirmed (r1, absmax 0.0): partitionable threefry (o0^o1), Eigen KC=288
// k-blocked left-fold sum order, f64-computed f32-rounded logs.
// r2: desynced blocks thrash L3 -> keep 256 blocks / 1 per CU, lockstep.
// r3 (prev best, 5.9ms): global divergent gather, ~20cyc/wave-gather (TA).
// r4/r6: wave-private LDS staging spilled to scratch (WRITE 45/25 GB) —
//     persistent per-thread offset blobs + long-lived float4s = VGPR blowup.
// r5: global_load_lds DMA bypassed L2/L3 (hbm ~= staged volume). Unusable.
// r7: SIMPLEST staging that can't spill: block-shared chunk double-buffer,
//     cooperative stage (1 live float4, offsets recomputed), one
//     __syncthreads per chunk, gather from LDS. No asm, no lambdas.

#define NSEQ 8192
#define LRES 256
#define QST  21
#define SPB  32                 // sequences per block
#define NTHREADS (SPB * QST)    // 672
#define CH   32                 // l per chunk
#define NCH  (LRES / CH)        // 8 chunks per step
#define STRIPW 688              // LDS words per a-strip (672 data + 16 pad)
#define BUFW (QST * STRIPW)     // 14448 words per chunk buffer
#define CHU4 168                // float4 units per (strip, chunk)
#define UNITS (QST * CHU4)      // 3528 float4 units per chunk
#define STRIPU4 1344            // float4 units per strip per row
#define ROWU4 28224             // float4 units per J row

// Per-l KC-crossing table: 255 = plain add; else threshold on b for boundary m.
struct KcTbl {
  unsigned char thr[LRES];
  constexpr KcTbl() : thr() {
    for (int i = 0; i < LRES; ++i) thr[i] = 255;
    for (int m = 1; m < 19; ++m) {
      int l = (288 * m) / 21;
      thr[l] = (unsigned char)(288 * m - 21 * l);
    }
  }
};
static constexpr KcTbl KC_TBL{};

__device__ __forceinline__ uint32_t rotl32(uint32_t v, uint32_t r) {
  return (v << r) | (v >> (32u - r));
}

// JAX/Random123 Threefry-2x32, 20 rounds.
__device__ __forceinline__ void threefry2x32(uint32_t k0, uint32_t k1,
                                             uint32_t c0, uint32_t c1,
                                             uint32_t& o0, uint32_t& o1) {
  uint32_t ks2 = k0 ^ k1 ^ 0x1BD11BDAu;
  uint32_t x0 = c0 + k0;
  uint32_t x1 = c1 + k1;
#define TF_ROUND(r) { x0 += x1; x1 = rotl32(x1, r); x1 ^= x0; }
  TF_ROUND(13u) TF_ROUND(15u) TF_ROUND(26u) TF_ROUND(6u)
  x0 += k1;  x1 += ks2 + 1u;
  TF_ROUND(17u) TF_ROUND(29u) TF_ROUND(16u) TF_ROUND(24u)
  x0 += ks2; x1 += k0 + 2u;
  TF_ROUND(13u) TF_ROUND(15u) TF_ROUND(26u) TF_ROUND(6u)
  x0 += k0;  x1 += k1 + 3u;
  TF_ROUND(17u) TF_ROUND(29u) TF_ROUND(16u) TF_ROUND(24u)
  x0 += k1;  x1 += ks2 + 4u;
  TF_ROUND(13u) TF_ROUND(15u) TF_ROUND(26u) TF_ROUND(6u)
  x0 += ks2; x1 += k0 + 5u;
#undef TF_ROUND
  o0 = x0; o1 = x1;
}

// JAX gumbel: -log(-log(uniform(tiny,1))), logs f64-computed f32-rounded.
__device__ __forceinline__ float gumbel_f32(uint32_t bits) {
  float f = __uint_as_float((bits >> 9) | 0x3f800000u) - 1.0f;
  float u = fmaxf(1.17549435e-38f, f + 1.17549435e-38f);
  float w = (float)log((double)u);
  float t = -w;
  float g = -(float)log((double)t);
  return g;
}

__global__ __launch_bounds__(NTHREADS, 1)
void gibbs_sweep(const float* __restrict__ X, const int* __restrict__ order,
                 const float* __restrict__ h, const float* __restrict__ J,
                 const float* __restrict__ betaPtr, float* __restrict__ out) {
  __shared__ __align__(16) float jchunk[2][BUFW];      // 115.6 KB, block-shared
  __shared__ uint32_t sbst[(LRES / 4) * SPB];          // packed states (8 KB)
  __shared__ float    vals[QST][SPB];
  __shared__ uint32_t tk0[LRES], tk1[LRES];            // per-step threefry keys
  __shared__ int      sord[LRES];

  const int nl  = threadIdx.x;       // 0..31 local sequence
  const int a   = threadIdx.y;       // 0..20 category
  const int tid = nl + SPB * a;      // 0..671
  const int n0  = blockIdx.x * SPB;
  const int n   = n0 + nl;
  const float beta = betaPtr[0];

  // ---- init: keys, order cache ----
  for (int t = tid; t < LRES; t += NTHREADS) {
    uint32_t o0, o1;
    threefry2x32(0u, 42u, 0u, (uint32_t)t, o0, o1);
    tk0[t] = o0; tk1[t] = o1;
    sord[t] = order[t];
  }

  // ---- init packed state from one-hot X ----
  for (int idx = tid; idx < (LRES / 4) * SPB; idx += NTHREADS) {
    int s  = idx & (SPB - 1);
    int wg = idx / SPB;
    uint32_t w = 0;
#pragma unroll
    for (int j = 0; j < 4; ++j) {
      int l = 4 * wg + j;
      const float* xp = X + ((size_t)(n0 + s) * LRES + l) * QST;
      int b = 0;
#pragma unroll
      for (int q = 0; q < QST; ++q) b = (xp[q] > 0.5f) ? q : b;
      w |= ((uint32_t)b) << (8 * j);
    }
    sbst[wg * SPB + s] = w;
  }
  __syncthreads();

  const float4* Jv = (const float4*)J;

  // ---- prologue: stage chunk 0 of step 0 into buffer 0 ----
  {
    const size_t rb = (size_t)sord[0] * ROWU4;
#pragma unroll
    for (int k = 0; k < 6; ++k) {
      int u = tid + NTHREADS * k;
      if (u < UNITS) {
        int aa = u / CHU4;
        int ww = u - aa * CHU4;
        float4 v = Jv[rb + (size_t)(aa * STRIPU4 + ww)];
        *(float4*)&jchunk[0][aa * STRIPW + 4 * ww] = v;
      }
    }
  }
  __syncthreads();

  // per-thread gather bases (own a-strip) for the two buffers
  const float* gbA = &jchunk[0][0] + a * STRIPW;
  const float* gbB = &jchunk[1][0] + a * STRIPW;

  // ---- sequential Gibbs sweep ----
  for (int t = 0; t < LRES; ++t) {
    const int i = sord[t];

    float tot = 0.0f, part = 0.0f;
#pragma unroll
    for (int c = 0; c < NCH; ++c) {
      // 1. cooperative stage of next chunk into the other buffer
      {
        const int nrow = (c < NCH - 1) ? i : sord[(t + 1) & (LRES - 1)];
        const int ncc  = (c < NCH - 1) ? c + 1 : 0;
        const size_t rb = (size_t)nrow * ROWU4 + (size_t)(ncc * CHU4);
        float* dst = &jchunk[(c + 1) & 1][0];
#pragma unroll
        for (int k = 0; k < 6; ++k) {
          int u = tid + NTHREADS * k;
          if (u < UNITS) {
            int aa = u / CHU4;
            int ww = u - aa * CHU4;
            float4 v = Jv[rb + (size_t)(aa * STRIPU4 + ww)];
            *(float4*)(dst + (aa * STRIPW + 4 * ww)) = v;
          }
        }
      }

      // 2. gather current chunk from LDS (Eigen KC=288 left-fold order)
      const float* gb = (c & 1) ? gbB : gbA;
#pragma unroll
      for (int lg = 0; lg < CH / 4; ++lg) {
        uint32_t w = sbst[(c * (CH / 4) + lg) * SPB + nl];
#pragma unroll
        for (int j = 0; j < 4; ++j) {
          const int l = c * CH + 4 * lg + j;   // compile-time after unroll
          uint32_t b = (w >> (8 * j)) & 0xffu;
          float jv = gb[(4 * lg + j) * QST + b];
          const int thr = KC_TBL.thr[l];       // folds at compile time
          if (thr == 255) {
            part += jv;
          } else if (thr == 0) {
            tot += part; part = jv;
          } else {
            if ((int)b >= thr) { tot += part; part = jv; }
            else               { part += jv; tot += part; part = 0.0f; }
          }
        }
      }
      __syncthreads();   // staged buffer ready; gathered buffer free
    }
    tot += part;

    float lo = h[i * QST + a] + tot;

    uint32_t o0, o1;
    threefry2x32(tk0[t], tk1[t], 0u, (uint32_t)(n * QST + a), o0, o1);
    float g = gumbel_f32(o0 ^ o1);

    vals[a][nl] = g + beta * lo;
    __syncthreads();

    if (a == 0) {                               // first-max argmax over 21
      float best = vals[0][nl];
      int bi = 0;
#pragma unroll
      for (int q = 1; q < QST; ++q) {
        float vv = vals[q][nl];
        if (vv > best) { best = vv; bi = q; }
      }
      unsigned char* bp = reinterpret_cast<unsigned char*>(sbst);
      bp[((i >> 2) * SPB + nl) * 4 + (i & 3)] = (unsigned char)bi;
    }
    __syncthreads();
  }

  // ---- expand packed state to one-hot f32 output ----
  const size_t base = (size_t)n0 * LRES * QST;
  for (int idx = tid; idx < SPB * LRES * QST; idx += NTHREADS) {
    int s   = idx / (LRES * QST);
    int rem = idx - s * (LRES * QST);
    int l   = rem / QST;
    int q   = rem - l * QST;
    uint32_t w = sbst[(l >> 2) * SPB + s];
    int b = (int)((w >> (8 * (l & 3))) & 0xffu);
    out[base + idx] = (b == q) ? 1.0f : 0.0f;
  }
}

extern "C" void kernel_launch(void* const* d_in, const int* in_sizes, int n_in,
                              void* d_out, int out_size, void* d_ws, size_t ws_size,
                              hipStream_t stream) {
  const float* X     = (const float*)d_in[0];
  const int*   order = (const int*)  d_in[1];
  const float* h     = (const float*)d_in[2];
  const float* J     = (const float*)d_in[3];
  const float* beta  = (const float*)d_in[4];
  float* out = (float*)d_out;

  dim3 grid(NSEQ / SPB);      // 256 blocks, 1 per CU
  dim3 block(SPB, QST);       // 32 x 21 = 672 threads
  hipLaunchKernelGGL(gibbs_sweep, grid, block, 0, stream, X, order, h, J, beta, out);
}

// Round 8
// 14197.028 us; speedup vs baseline: 1.2500x; 1.2500x over previous
//
#include <hip/hip_runtime.h>
#include <stdint.h>
#include <math.h>

// plmDCA one Gibbs sweep — bitwise-faithful replay of the JAX reference.
// Confirmed (r1, absmax 0.0): partitionable threefry (o0^o1), Eigen KC=288
// k-blocked left-fold sum order, f64-computed f32-rounded logs.
// r2: desynced blocks thrash caches. r3 (best, 5.9ms): divergent global
// gather, drift-robust via temporal reuse. r4-r7: ALL staging variants hit
// the same wall (FETCH 10-20GB, WRITE 15-45GB) regardless of mechanism
// (reg-staged / DMA / block-shared) -> NOT spill; it's BLOCK DRIFT: one-touch
// streaming has no reuse, drifting blocks demand different rows, L2 churns.
// r8: r7's spill-proof staging + per-step PACING barrier (8 groups of 32
// blocks, monotonic counters in d_ws, timeout escape; pacing-only => zero
// correctness risk). Chunk-0 stage hoisted above the barrier.

#define NSEQ 8192
#define LRES 256
#define QST  21
#define SPB  32                 // sequences per block
#define NTHREADS (SPB * QST)    // 672
#define CH   32                 // l per chunk
#define NCH  (LRES / CH)        // 8 chunks per step
#define STRIPW 676              // LDS words per a-strip (672 data + 4 pad)
#define BUFW (QST * STRIPW)     // 14196 words per chunk buffer
#define CHU4 168                // float4 units per (strip, chunk)
#define UNITS (QST * CHU4)      // 3528 float4 units per chunk
#define STRIPU4 1344            // float4 units per strip per row
#define ROWU4 28224             // float4 units per J row
#define NGRP 8                  // pacing groups (XCD heuristic)
#define GRPSZ (256 / NGRP)      // 32 blocks per group

// Per-l KC-crossing table: 255 = plain add; else threshold on b for boundary m.
struct KcTbl {
  unsigned char thr[LRES];
  constexpr KcTbl() : thr() {
    for (int i = 0; i < LRES; ++i) thr[i] = 255;
    for (int m = 1; m < 19; ++m) {
      int l = (288 * m) / 21;
      thr[l] = (unsigned char)(288 * m - 21 * l);
    }
  }
};
static constexpr KcTbl KC_TBL{};

__device__ __forceinline__ uint32_t rotl32(uint32_t v, uint32_t r) {
  return (v << r) | (v >> (32u - r));
}

// JAX/Random123 Threefry-2x32, 20 rounds.
__device__ __forceinline__ void threefry2x32(uint32_t k0, uint32_t k1,
                                             uint32_t c0, uint32_t c1,
                                             uint32_t& o0, uint32_t& o1) {
  uint32_t ks2 = k0 ^ k1 ^ 0x1BD11BDAu;
  uint32_t x0 = c0 + k0;
  uint32_t x1 = c1 + k1;
#define TF_ROUND(r) { x0 += x1; x1 = rotl32(x1, r); x1 ^= x0; }
  TF_ROUND(13u) TF_ROUND(15u) TF_ROUND(26u) TF_ROUND(6u)
  x0 += k1;  x1 += ks2 + 1u;
  TF_ROUND(17u) TF_ROUND(29u) TF_ROUND(16u) TF_ROUND(24u)
  x0 += ks2; x1 += k0 + 2u;
  TF_ROUND(13u) TF_ROUND(15u) TF_ROUND(26u) TF_ROUND(6u)
  x0 += k0;  x1 += k1 + 3u;
  TF_ROUND(17u) TF_ROUND(29u) TF_ROUND(16u) TF_ROUND(24u)
  x0 += k1;  x1 += ks2 + 4u;
  TF_ROUND(13u) TF_ROUND(15u) TF_ROUND(26u) TF_ROUND(6u)
  x0 += ks2; x1 += k0 + 5u;
#undef TF_ROUND
  o0 = x0; o1 = x1;
}

// JAX gumbel: -log(-log(uniform(tiny,1))), logs f64-computed f32-rounded.
__device__ __forceinline__ float gumbel_f32(uint32_t bits) {
  float f = __uint_as_float((bits >> 9) | 0x3f800000u) - 1.0f;
  float u = fmaxf(1.17549435e-38f, f + 1.17549435e-38f);
  float w = (float)log((double)u);
  float t = -w;
  float g = -(float)log((double)t);
  return g;
}

// Cooperative stage of one (row, chunk) into LDS buffer. Scalars only.
__device__ __forceinline__ void stage_chunk(const float4* __restrict__ Jv,
                                            size_t rb, float* __restrict__ dst,
                                            int tid) {
#pragma unroll
  for (int k = 0; k < 6; ++k) {
    int u = tid + NTHREADS * k;
    if (u < UNITS) {
      int aa = u / CHU4;
      int ww = u - aa * CHU4;
      float4 v = Jv[rb + (size_t)(aa * STRIPU4 + ww)];
      *(float4*)(dst + (aa * STRIPW + 4 * ww)) = v;
    }
  }
}

__global__ __launch_bounds__(NTHREADS, 1)
void gibbs_sweep(const float* __restrict__ X, const int* __restrict__ order,
                 const float* __restrict__ h, const float* __restrict__ J,
                 const float* __restrict__ betaPtr, float* __restrict__ out,
                 unsigned int* __restrict__ pace) {
  __shared__ __align__(16) float jchunk[2][BUFW];      // 113.6 KB block-shared
  __shared__ uint32_t sbst[(LRES / 4) * SPB];          // packed states (8 KB)
  __shared__ float    vals[QST][SPB];
  __shared__ uint32_t tk0[LRES], tk1[LRES];            // per-step threefry keys
  __shared__ int      sord[LRES];

  const int nl  = threadIdx.x;       // 0..31 local sequence
  const int a   = threadIdx.y;       // 0..20 category
  const int tid = nl + SPB * a;      // 0..671
  const int n0  = blockIdx.x * SPB;
  const int n   = n0 + nl;
  const int grp = blockIdx.x & (NGRP - 1);   // XCD round-robin heuristic
  const float beta = betaPtr[0];
  unsigned int* gcnt = pace + grp * 32;      // 128B-spaced counter

  // ---- init: keys, order cache ----
  for (int t = tid; t < LRES; t += NTHREADS) {
    uint32_t o0, o1;
    threefry2x32(0u, 42u, 0u, (uint32_t)t, o0, o1);
    tk0[t] = o0; tk1[t] = o1;
    sord[t] = order[t];
  }

  // ---- init packed state from one-hot X ----
  for (int idx = tid; idx < (LRES / 4) * SPB; idx += NTHREADS) {
    int s  = idx & (SPB - 1);
    int wg = idx / SPB;
    uint32_t w = 0;
#pragma unroll
    for (int j = 0; j < 4; ++j) {
      int l = 4 * wg + j;
      const float* xp = X + ((size_t)(n0 + s) * LRES + l) * QST;
      int b = 0;
#pragma unroll
      for (int q = 0; q < QST; ++q) b = (xp[q] > 0.5f) ? q : b;
      w |= ((uint32_t)b) << (8 * j);
    }
    sbst[wg * SPB + s] = w;
  }
  __syncthreads();

  const float4* Jv = (const float4*)J;

  // ---- sequential Gibbs sweep ----
  for (int t = 0; t < LRES; ++t) {
    const int i = sord[t];
    const size_t rowb = (size_t)i * ROWU4;

    // stage chunk 0 (reads constant J only -> safe before pacing barrier;
    // previous step's last gather from buf0 ended before the argmax barrier)
    stage_chunk(Jv, rowb, &jchunk[0][0], tid);

    // pacing barrier: align the 32 group blocks on step t (pacing ONLY —
    // no data dependency; timeout escape keeps termination unconditional)
    if (tid == 0) {
      __hip_atomic_fetch_add(gcnt, 1u, __ATOMIC_RELAXED,
                             __HIP_MEMORY_SCOPE_AGENT);
      const unsigned int target = (unsigned int)(GRPSZ * (t + 1));
      unsigned int spin = 0;
      while (__hip_atomic_load(gcnt, __ATOMIC_RELAXED,
                               __HIP_MEMORY_SCOPE_AGENT) < target &&
             spin < (1u << 20)) {
        ++spin;
        __builtin_amdgcn_s_sleep(1);
      }
    }
    __syncthreads();   // releases block; also publishes staged chunk 0

    float tot = 0.0f, part = 0.0f;
#pragma unroll
    for (int c = 0; c < NCH; ++c) {
      // 1. stage next chunk into the other buffer (none at c==7)
      if (c < NCH - 1)
        stage_chunk(Jv, rowb + (size_t)((c + 1) * CHU4),
                    &jchunk[(c + 1) & 1][0], tid);

      // 2. gather current chunk from LDS (Eigen KC=288 left-fold order)
      const float* gb = &jchunk[c & 1][0] + a * STRIPW;
#pragma unroll
      for (int lg = 0; lg < CH / 4; ++lg) {
        uint32_t w = sbst[(c * (CH / 4) + lg) * SPB + nl];
#pragma unroll
        for (int j = 0; j < 4; ++j) {
          const int l = c * CH + 4 * lg + j;   // compile-time after unroll
          uint32_t b = (w >> (8 * j)) & 0xffu;
          float jv = gb[(4 * lg + j) * QST + b];
          const int thr = KC_TBL.thr[l];       // folds at compile time
          if (thr == 255) {
            part += jv;
          } else if (thr == 0) {
            tot += part; part = jv;
          } else {
            if ((int)b >= thr) { tot += part; part = jv; }
            else               { part += jv; tot += part; part = 0.0f; }
          }
        }
      }
      __syncthreads();   // staged buffer ready; gathered buffer reusable
    }
    tot += part;

    float lo = h[i * QST + a] + tot;

    uint32_t o0, o1;
    threefry2x32(tk0[t], tk1[t], 0u, (uint32_t)(n * QST + a), o0, o1);
    float g = gumbel_f32(o0 ^ o1);

    vals[a][nl] = g + beta * lo;
    __syncthreads();

    if (a == 0) {                               // first-max argmax over 21
      float best = vals[0][nl];
      int bi = 0;
#pragma unroll
      for (int q = 1; q < QST; ++q) {
        float vv = vals[q][nl];
        if (vv > best) { best = vv; bi = q; }
      }
      unsigned char* bp = reinterpret_cast<unsigned char*>(sbst);
      bp[((i >> 2) * SPB + nl) * 4 + (i & 3)] = (unsigned char)bi;
    }
    __syncthreads();
  }

  // ---- expand packed state to one-hot f32 output ----
  const size_t base = (size_t)n0 * LRES * QST;
  for (int idx = tid; idx < SPB * LRES * QST; idx += NTHREADS) {
    int s   = idx / (LRES * QST);
    int rem = idx - s * (LRES * QST);
    int l   = rem / QST;
    int q   = rem - l * QST;
    uint32_t w = sbst[(l >> 2) * SPB + s];
    int b = (int)((w >> (8 * (l & 3))) & 0xffu);
    out[base + idx] = (b == q) ? 1.0f : 0.0f;
  }
}

extern "C" void kernel_launch(void* const* d_in, const int* in_sizes, int n_in,
                              void* d_out, int out_size, void* d_ws, size_t ws_size,
                              hipStream_t stream) {
  const float* X     = (const float*)d_in[0];
  const int*   order = (const int*)  d_in[1];
  const float* h     = (const float*)d_in[2];
  const float* J     = (const float*)d_in[3];
  const float* beta  = (const float*)d_in[4];
  float* out = (float*)d_out;
  unsigned int* pace = (unsigned int*)d_ws;

  // zero the pacing counters every launch (deterministic; graph-capturable)
  hipMemsetAsync(pace, 0, NGRP * 32 * sizeof(unsigned int), stream);

  dim3 grid(NSEQ / SPB);      // 256 blocks, 1 per CU (LDS-forced), co-resident
  dim3 block(SPB, QST);       // 32 x 21 = 672 threads
  hipLaunchKernelGGL(gibbs_sweep, grid, block, 0, stream,
                     X, order, h, J, beta, out, pace);
}